// Round 1
// baseline (82.172 us; speedup 1.0000x reference)
//
#include <hip/hip_runtime.h>

// Problem constants (reference: B=8, E=16, H=256, W=256)
#define NB 8
#define NE 16
#define HW (256 * 256)        // pixels per sample
#define HW4 (HW / 4)          // float4 groups per sample
#define NPIX (NB * HW)        // total pixels = 524288
#define NT4 (NPIX / 4)        // total float4 pixel-groups = 131072

// val(pixel) = mean_e |f_e - o| - 0.5 * mean_{e,e'} |f_e - f_e'|
//            = (1/16) * S1 - (1/256) * S2_unordered_pairs
// final out  = (1/NPIX) * sum over pixels of val

__global__ __launch_bounds__(256) void crps_kernel(
    const float* __restrict__ fore,   // [B, E, HW]
    const float* __restrict__ obs,    // [B, HW]
    float* __restrict__ out)          // [1]
{
    const int idx = blockIdx.x * blockDim.x + threadIdx.x;   // 0 .. NT4-1
    const int b  = idx >> 14;          // idx / (HW/4), HW4 = 16384
    const int p4 = idx & (HW4 - 1);    // float4 offset within sample

    const float4* fore4 = reinterpret_cast<const float4*>(fore);
    const float4* obs4  = reinterpret_cast<const float4*>(obs);

    // Load 16 ensemble members (each a coalesced float4 across the wave)
    float v[NE][4];
#pragma unroll
    for (int e = 0; e < NE; ++e) {
        float4 t = fore4[(size_t)(b * NE + e) * HW4 + p4];
        v[e][0] = t.x; v[e][1] = t.y; v[e][2] = t.z; v[e][3] = t.w;
    }
    float4 ot = obs4[(size_t)b * HW4 + p4];
    float o[4] = { ot.x, ot.y, ot.z, ot.w };

    float acc = 0.0f;
#pragma unroll
    for (int c = 0; c < 4; ++c) {
        float s1 = 0.0f;
#pragma unroll
        for (int e = 0; e < NE; ++e)
            s1 += fabsf(v[e][c] - o[c]);
        float s2 = 0.0f;
#pragma unroll
        for (int i = 0; i < NE; ++i)
#pragma unroll
            for (int j = i + 1; j < NE; ++j)
                s2 += fabsf(v[i][c] - v[j][c]);
        acc += s1 * (1.0f / NE) - s2 * (1.0f / (NE * NE));
    }

    // Wave (64-lane) shuffle reduction
#pragma unroll
    for (int off = 32; off > 0; off >>= 1)
        acc += __shfl_down(acc, off);

    __shared__ float smem[4];          // 256 threads = 4 waves
    const int lane = threadIdx.x & 63;
    const int wave = threadIdx.x >> 6;
    if (lane == 0) smem[wave] = acc;
    __syncthreads();
    if (threadIdx.x == 0) {
        float s = smem[0] + smem[1] + smem[2] + smem[3];
        atomicAdd(out, s * (1.0f / NPIX));   // one device-scope atomic per block
    }
}

extern "C" void kernel_launch(void* const* d_in, const int* in_sizes, int n_in,
                              void* d_out, int out_size, void* d_ws, size_t ws_size,
                              hipStream_t stream) {
    const float* fore = (const float*)d_in[0];   // [8,16,256,256] f32
    const float* obs  = (const float*)d_in[1];   // [8,256,256] f32
    float* out = (float*)d_out;

    // d_out is re-poisoned to 0xAA before every timed launch — zero it.
    hipMemsetAsync(out, 0, sizeof(float), stream);

    const int threads = 256;
    const int blocks  = NT4 / threads;   // 131072 / 256 = 512
    crps_kernel<<<blocks, threads, 0, stream>>>(fore, obs, out);
}